// Round 8
// baseline (120.160 us; speedup 1.0000x reference)
//
#include <hip/hip_runtime.h>
#include <math.h>

#define NPTS   4096
#define BATCH  16
#define BLK    512
#define CS     8                         // column splits
#define COLS_PER_BLK (NPTS / CS)         // 512
#define TPB    (COLS_PER_BLK / 32)       // 16 col tiles per block
#define ROWS_PER_BLK 512                 // 8 waves x 2 row-tiles x 32 rows
#define PANELS (NPTS / ROWS_PER_BLK)     // 8

typedef __attribute__((ext_vector_type(8)))  short bf16x8;
typedef __attribute__((ext_vector_type(16))) float f32x16;

static __device__ __forceinline__ unsigned short f2bf(float x) {
    unsigned u = __float_as_uint(x);
    unsigned r = 0x7FFFu + ((u >> 16) & 1u);     // RNE
    return (unsigned short)((u + r) >> 16);
}
static __device__ __forceinline__ float bf2f(unsigned short h) {
    return __uint_as_float(((unsigned)h) << 16);
}

// ---------------------------------------------------------------------------
// One mfma_f32_32x32x16_bf16 per 32x32 tile = full distance sub-matrix
// (k-slot map validated rounds 4-7, absmax 0.0):
//   k0-2: A=-2ph,B=th  k3-5: A=-2pl,B=th  k6-8: A=-2ph,B=tl
//   k9,10: A=pph,ppl B=1   k11,12: A=1 B=tth,ttl   k13-15: 0
// Two passes (grid z = dir, A/B swapped): all mins are register row-mins.
// THIS ROUND: MFMA via inline asm with "v" constraints — rounds 4-7 all
// showed VGPR_Count=32, i.e. LLVM put builtin accumulators in AGPRs and
// burned ~3x VALU on v_accvgpr_read/write per tile. Unified gfx950 RF
// allows D/C in VGPRs. Consumption via explicit v_min3_f32 asm (2 tiles
// per instr); order mfma,mfma,mfma,mfma,s_nop,min3... covers the MFMA
// vdst-read-after-write hazard (>=24 cy gap).
// ws: float partial[dir][b][cs][4096] (4 MB), every slot written once.
// ---------------------------------------------------------------------------

#define MFMA_V(D, A, Bf, C) \
    asm volatile("v_mfma_f32_32x32x16_bf16 %0, %1, %2, %3" \
                 : "=&v"(D) : "v"(A), "v"(Bf), "v"(C))

static __device__ __forceinline__ bf16x8 make_afrag(const float* mp, int l) {
    const short one = (short)0x3F80;
    float x = mp[0], y = mp[1], z = mp[2];
    unsigned short hx = f2bf(x), hy = f2bf(y), hz = f2bf(z);
    unsigned short lx = f2bf(x - bf2f(hx));
    unsigned short ly = f2bf(y - bf2f(hy));
    unsigned short lz = f2bf(z - bf2f(hz));
    unsigned short n2hx = f2bf(-2.0f * bf2f(hx));
    unsigned short n2hy = f2bf(-2.0f * bf2f(hy));
    unsigned short n2hz = f2bf(-2.0f * bf2f(hz));
    unsigned short n2lx = f2bf(-2.0f * bf2f(lx));
    unsigned short n2ly = f2bf(-2.0f * bf2f(ly));
    unsigned short n2lz = f2bf(-2.0f * bf2f(lz));
    float pp = fmaf(z, z, fmaf(y, y, x * x));
    unsigned short pph = f2bf(pp);
    unsigned short ppl = f2bf(pp - bf2f(pph));
    if (l < 32)
        return (bf16x8){(short)n2hx, (short)n2hy, (short)n2hz,
                        (short)n2lx, (short)n2ly, (short)n2lz,
                        (short)n2hx, (short)n2hy};
    else
        return (bf16x8){(short)n2hz, (short)pph, (short)ppl, one, one, 0, 0, 0};
}

__global__ __launch_bounds__(BLK, 3) void chamfer_mfma(
    const float* __restrict__ pred, const float* __restrict__ target,
    float* __restrict__ partial)
{
    __shared__ __align__(16) bf16x8 sB[TPB * 64];   // 16 KB B-fragments

    const int bx    = blockIdx.x;
    const int cs    = bx & (CS - 1);
    const int panel = bx >> 3;
    const int b     = blockIdx.y;
    const int dir   = blockIdx.z;
    const int t     = threadIdx.x;
    const int w     = t >> 6;
    const int l     = t & 63;
    const short one = (short)0x3F80;

    const float* mine  = dir ? target : pred;
    const float* other = dir ? pred : target;

    // ---- stage B fragments for this block's 512 columns (2 iters) ----
    const int colbase = cs * COLS_PER_BLK;
    for (int e = t; e < TPB * 64; e += BLK) {
        const int el   = e & 63;
        const int tile = e >> 6;
        const int col  = colbase + tile * 32 + (el & 31);
        const float* tp = other + ((size_t)b * NPTS + col) * 3;
        float x = tp[0], y = tp[1], z = tp[2];
        unsigned short hx = f2bf(x), hy = f2bf(y), hz = f2bf(z);
        unsigned short lx = f2bf(x - bf2f(hx));
        unsigned short ly = f2bf(y - bf2f(hy));
        unsigned short lz = f2bf(z - bf2f(hz));
        float tt = fmaf(z, z, fmaf(y, y, x * x));
        unsigned short th = f2bf(tt);
        unsigned short tl = f2bf(tt - bf2f(th));
        bf16x8 v;
        if (el < 32)
            v = (bf16x8){(short)hx, (short)hy, (short)hz,
                         (short)hx, (short)hy, (short)hz,
                         (short)lx, (short)ly};
        else
            v = (bf16x8){(short)lz, one, one, (short)th, (short)tl, 0, 0, 0};
        sB[e] = v;
    }

    // ---- A fragments: this wave's 2 row-tiles (64 rows) ----
    const int rowbase = panel * ROWS_PER_BLK + w * 64;
    const size_t mb = (size_t)b * NPTS;
    bf16x8 af0 = make_afrag(mine + (mb + rowbase +      (l & 31)) * 3, l);
    bf16x8 af1 = make_afrag(mine + (mb + rowbase + 32 + (l & 31)) * 3, l);

    __syncthreads();

    f32x16 rm0, rm1, zacc;
    #pragma unroll
    for (int i = 0; i < 16; ++i) { rm0[i] = INFINITY; rm1[i] = INFINITY; zacc[i] = 0.0f; }

    // ---- sweep col tiles in pairs: 2 ds_read + 4 MFMA + 32 v_min3 ----
    for (int tp2 = 0; tp2 < TPB; tp2 += 2) {
        bf16x8 b0 = sB[(tp2 + 0) * 64 + l];
        bf16x8 b1 = sB[(tp2 + 1) * 64 + l];
        f32x16 a00, a01, a10, a11;
        MFMA_V(a00, af0, b0, zacc);
        MFMA_V(a01, af0, b1, zacc);
        MFMA_V(a10, af1, b0, zacc);
        MFMA_V(a11, af1, b1, zacc);
        asm volatile("s_nop 7");
        #pragma unroll
        for (int i = 0; i < 16; ++i)
            asm volatile("v_min3_f32 %0, %1, %2, %0"
                         : "+v"(rm0[i]) : "v"(a00[i]), "v"(a01[i]));
        #pragma unroll
        for (int i = 0; i < 16; ++i)
            asm volatile("v_min3_f32 %0, %1, %2, %0"
                         : "+v"(rm1[i]) : "v"(a10[i]), "v"(a11[i]));
    }

    // ---- rowmin: reduce across the 32 col-lanes of each half, store ----
    const int h = l >> 5;
    float* pb = partial + (((size_t)dir * BATCH + b) * CS + cs) * NPTS + rowbase;
    #pragma unroll
    for (int j = 0; j < 2; ++j) {
        f32x16& rm = j ? rm1 : rm0;
        #pragma unroll
        for (int i = 0; i < 16; ++i) {
            float v = rm[i];
            v = fminf(v, __shfl_xor(v, 1, 64));
            v = fminf(v, __shfl_xor(v, 2, 64));
            v = fminf(v, __shfl_xor(v, 4, 64));
            v = fminf(v, __shfl_xor(v, 8, 64));
            v = fminf(v, __shfl_xor(v, 16, 64));
            rm[i] = v;
        }
        if ((l & 31) == 0) {
            #pragma unroll
            for (int i = 0; i < 16; ++i)
                pb[j * 32 + (i & 3) + 8 * (i >> 2) + 4 * h] = rm[i];
        }
    }
}

// min over CS column-split partials, clamp, sum, scale, atomicAdd out.
__global__ __launch_bounds__(256) void chamfer_sum(
    const float* __restrict__ partial, float* __restrict__ out)
{
    __shared__ float wsum[4];
    const int gid = blockIdx.x * 256 + threadIdx.x;   // 32 blocks = 8192 threads

    float s = 0.0f;
    for (int i = gid; i < 2 * BATCH * NPTS; i += 8192) {
        const int db  = i >> 12;           // (dir, b) pair 0..31
        const int row = i & (NPTS - 1);
        const float* p = partial + (size_t)db * CS * NPTS + row;
        float v = p[0];
        #pragma unroll
        for (int c = 1; c < CS; ++c) v = fminf(v, p[(size_t)c * NPTS]);
        s += fmaxf(v, 0.0f);
    }

    #pragma unroll
    for (int off = 32; off > 0; off >>= 1)
        s += __shfl_down(s, off, 64);

    if ((threadIdx.x & 63) == 0) wsum[threadIdx.x >> 6] = s;
    __syncthreads();

    if (threadIdx.x == 0) {
        float acc = wsum[0] + wsum[1] + wsum[2] + wsum[3];
        atomicAdd(out, acc * (1.0f / ((float)BATCH * (float)NPTS)));
    }
}

extern "C" void kernel_launch(void* const* d_in, const int* in_sizes, int n_in,
                              void* d_out, int out_size, void* d_ws, size_t ws_size,
                              hipStream_t stream) {
    const float* pred   = (const float*)d_in[0];
    const float* target = (const float*)d_in[1];
    float* out = (float*)d_out;
    float* partial = (float*)d_ws;                    // 4 MB, fully overwritten

    hipMemsetAsync(out, 0, sizeof(float), stream);

    chamfer_mfma<<<dim3(CS * PANELS, BATCH, 2), BLK, 0, stream>>>(
        pred, target, partial);
    chamfer_sum<<<dim3(32), 256, 0, stream>>>(partial, out);
}

// Round 9
// 97.960 us; speedup vs baseline: 1.2266x; 1.2266x over previous
//
#include <hip/hip_runtime.h>
#include <math.h>

#define NPTS   4096
#define BATCH  16
#define BLK    256                       // 4 waves
#define CS     8                         // column splits
#define COLS_PER_BLK (NPTS / CS)         // 512
#define TPB    (COLS_PER_BLK / 32)       // 16 col tiles per block
#define ROWS_PER_BLK 256                 // 4 waves x 2 row-tiles x 32 rows
#define PANELS (NPTS / ROWS_PER_BLK)     // 16

typedef __attribute__((ext_vector_type(8)))  short bf16x8;
typedef __attribute__((ext_vector_type(16))) float f32x16;

static __device__ __forceinline__ unsigned short f2bf(float x) {
    unsigned u = __float_as_uint(x);
    unsigned r = 0x7FFFu + ((u >> 16) & 1u);     // RNE
    return (unsigned short)((u + r) >> 16);
}
static __device__ __forceinline__ float bf2f(unsigned short h) {
    return __uint_as_float(((unsigned)h) << 16);
}
static __device__ __forceinline__ float min3f(float a, float b, float c) {
    return fminf(fminf(a, b), c);                // fuses to v_min3_f32
}
// register tree-min over one tile's 16 acc elements (this lane's column slice)
static __device__ __forceinline__ float tile_colmin(const f32x16& a) {
    float t0 = min3f(a[0],  a[1],  a[2]);
    float t1 = min3f(a[3],  a[4],  a[5]);
    float t2 = min3f(a[6],  a[7],  a[8]);
    float t3 = min3f(a[9],  a[10], a[11]);
    float t4 = min3f(a[12], a[13], a[14]);
    return fminf(min3f(t0, t1, t2), min3f(t3, t4, a[15]));
}

// ---------------------------------------------------------------------------
// SINGLE PASS: one mfma_f32_32x32x16_bf16 per 32x32 tile of D = |p-t|^2
// (k-slot map validated rounds 4-8, absmax 0.0):
//   k0-2: A=-2ph,B=th  k3-5: A=-2pl,B=th  k6-8: A=-2ph,B=tl
//   k9,10: A=pph,ppl B=1   k11,12: A=1 B=tth,ttl   k13-15: 0
// rowmin (pred->target) stays in registers; colmin (target->pred) via
// min3-tree + shfl_xor(32) + LDS atomicMin, panels combined by global
// atomicMin. Builtin MFMA (best measured codegen: VGPR=32, occ 66%).
// Forensics: single-pass hybrid (R4p, ~27us) beat 2-pass rowmin (R6p 34,
// R7 46.7) and asm (R8 60.8). This round: +2 rowtiles/wave (shared
// ds_read), BLK=256/CS=8 for 8 blocks/CU, half the colmin atomics.
// ws: [0,256KB) gcolmin uint bits [b][4096] (sentinel 0x7F);
//     [256KB, 256KB+2MB) rowmin partial float [b][cs][4096], each written once.
// ---------------------------------------------------------------------------

static __device__ __forceinline__ bf16x8 make_afrag(const float* mp, int l) {
    const short one = (short)0x3F80;
    float x = mp[0], y = mp[1], z = mp[2];
    unsigned short hx = f2bf(x), hy = f2bf(y), hz = f2bf(z);
    unsigned short lx = f2bf(x - bf2f(hx));
    unsigned short ly = f2bf(y - bf2f(hy));
    unsigned short lz = f2bf(z - bf2f(hz));
    unsigned short n2hx = f2bf(-2.0f * bf2f(hx));
    unsigned short n2hy = f2bf(-2.0f * bf2f(hy));
    unsigned short n2hz = f2bf(-2.0f * bf2f(hz));
    unsigned short n2lx = f2bf(-2.0f * bf2f(lx));
    unsigned short n2ly = f2bf(-2.0f * bf2f(ly));
    unsigned short n2lz = f2bf(-2.0f * bf2f(lz));
    float pp = fmaf(z, z, fmaf(y, y, x * x));
    unsigned short pph = f2bf(pp);
    unsigned short ppl = f2bf(pp - bf2f(pph));
    if (l < 32)
        return (bf16x8){(short)n2hx, (short)n2hy, (short)n2hz,
                        (short)n2lx, (short)n2ly, (short)n2lz,
                        (short)n2hx, (short)n2hy};
    else
        return (bf16x8){(short)n2hz, (short)pph, (short)ppl, one, one, 0, 0, 0};
}

__global__ __launch_bounds__(BLK) void chamfer_mfma(
    const float* __restrict__ pred, const float* __restrict__ target,
    unsigned* __restrict__ gcolmin, float* __restrict__ partial_row)
{
    __shared__ __align__(16) bf16x8 sB[TPB * 64];   // 16 KB B-fragments
    __shared__ unsigned colmin[COLS_PER_BLK];       // 2 KB

    const int bx    = blockIdx.x;
    const int cs    = bx & (CS - 1);
    const int panel = bx >> 3;
    const int b     = blockIdx.y;
    const int t     = threadIdx.x;
    const int w     = t >> 6;
    const int l     = t & 63;
    const short one = (short)0x3F80;

    for (int i = t; i < COLS_PER_BLK; i += BLK) colmin[i] = 0x7F800000u;

    // ---- stage B fragments for this block's 512 target columns ----
    const int colbase = cs * COLS_PER_BLK;
    for (int e = t; e < TPB * 64; e += BLK) {
        const int el   = e & 63;
        const int tile = e >> 6;
        const int col  = colbase + tile * 32 + (el & 31);
        const float* tp = target + ((size_t)b * NPTS + col) * 3;
        float x = tp[0], y = tp[1], z = tp[2];
        unsigned short hx = f2bf(x), hy = f2bf(y), hz = f2bf(z);
        unsigned short lx = f2bf(x - bf2f(hx));
        unsigned short ly = f2bf(y - bf2f(hy));
        unsigned short lz = f2bf(z - bf2f(hz));
        float tt = fmaf(z, z, fmaf(y, y, x * x));
        unsigned short th = f2bf(tt);
        unsigned short tl = f2bf(tt - bf2f(th));
        bf16x8 v;
        if (el < 32)
            v = (bf16x8){(short)hx, (short)hy, (short)hz,
                         (short)hx, (short)hy, (short)hz,
                         (short)lx, (short)ly};
        else
            v = (bf16x8){(short)lz, one, one, (short)th, (short)tl, 0, 0, 0};
        sB[e] = v;
    }

    // ---- A fragments: this wave's 2 row-tiles of pred rows ----
    const int rowbase = panel * ROWS_PER_BLK + w * 64;
    const size_t mb = (size_t)b * NPTS;
    bf16x8 af0 = make_afrag(pred + (mb + rowbase +      (l & 31)) * 3, l);
    bf16x8 af1 = make_afrag(pred + (mb + rowbase + 32 + (l & 31)) * 3, l);

    __syncthreads();

    f32x16 rm0, rm1, zacc;
    #pragma unroll
    for (int i = 0; i < 16; ++i) { rm0[i] = INFINITY; rm1[i] = INFINITY; zacc[i] = 0.0f; }

    // ---- sweep col tiles in pairs: 2 ds_read, 4 MFMA, rowmin min3,
    //      colmin trees combined across rowtiles -> 1 atomic round/coltile ----
    for (int tp2 = 0; tp2 < TPB; tp2 += 2) {
        bf16x8 b0 = sB[(tp2 + 0) * 64 + l];
        bf16x8 b1 = sB[(tp2 + 1) * 64 + l];
        f32x16 a00 = __builtin_amdgcn_mfma_f32_32x32x16_bf16(af0, b0, zacc, 0, 0, 0);
        f32x16 a01 = __builtin_amdgcn_mfma_f32_32x32x16_bf16(af0, b1, zacc, 0, 0, 0);
        f32x16 a10 = __builtin_amdgcn_mfma_f32_32x32x16_bf16(af1, b0, zacc, 0, 0, 0);
        f32x16 a11 = __builtin_amdgcn_mfma_f32_32x32x16_bf16(af1, b1, zacc, 0, 0, 0);

        #pragma unroll
        for (int i = 0; i < 16; ++i) rm0[i] = min3f(a00[i], a01[i], rm0[i]);
        #pragma unroll
        for (int i = 0; i < 16; ++i) rm1[i] = min3f(a10[i], a11[i], rm1[i]);

        // colmin for coltile tp2 (from a00,a10) and tp2+1 (from a01,a11)
        float c0 = fmaxf(fminf(tile_colmin(a00), tile_colmin(a10)), 0.0f);
        float c1 = fmaxf(fminf(tile_colmin(a01), tile_colmin(a11)), 0.0f);
        c0 = fminf(c0, __shfl_xor(c0, 32, 64));
        c1 = fminf(c1, __shfl_xor(c1, 32, 64));
        if (l < 32) {
            atomicMin(&colmin[(tp2 + 0) * 32 + l], __float_as_uint(c0));
            atomicMin(&colmin[(tp2 + 1) * 32 + l], __float_as_uint(c1));
        }
    }

    // ---- rowmin: reduce across the 32 col-lanes of each half, store ----
    const int h = l >> 5;
    float* pb = partial_row + ((size_t)b * CS + cs) * NPTS + rowbase;
    #pragma unroll
    for (int j = 0; j < 2; ++j) {
        f32x16& rm = j ? rm1 : rm0;
        #pragma unroll
        for (int i = 0; i < 16; ++i) {
            float v = rm[i];
            v = fminf(v, __shfl_xor(v, 1, 64));
            v = fminf(v, __shfl_xor(v, 2, 64));
            v = fminf(v, __shfl_xor(v, 4, 64));
            v = fminf(v, __shfl_xor(v, 8, 64));
            v = fminf(v, __shfl_xor(v, 16, 64));
            rm[i] = v;
        }
        if ((l & 31) == 0) {
            #pragma unroll
            for (int i = 0; i < 16; ++i)
                pb[j * 32 + (i & 3) + 8 * (i >> 2) + 4 * h] = rm[i];
        }
    }

    // ---- flush block-local colmin to global (across 16 panels) ----
    __syncthreads();
    unsigned* cb = gcolmin + (size_t)b * NPTS + colbase;
    for (int i = t; i < COLS_PER_BLK; i += BLK)
        atomicMin(&cb[i], colmin[i]);
}

// Final: rowmin = min over CS partials (clamp); colmin already clamped. Sum.
__global__ __launch_bounds__(256) void chamfer_sum(
    const unsigned* __restrict__ gcolmin, const float* __restrict__ partial_row,
    float* __restrict__ out)
{
    __shared__ float wsum[4];
    const int gid = blockIdx.x * 256 + threadIdx.x;   // 32 blocks = 8192 threads

    float s = 0.0f;
    for (int i = gid; i < BATCH * NPTS; i += 8192) {
        const int b   = i >> 12;
        const int row = i & (NPTS - 1);
        const float* p = partial_row + (size_t)b * CS * NPTS + row;
        float v = p[0];
        #pragma unroll
        for (int c = 1; c < CS; ++c) v = fminf(v, p[(size_t)c * NPTS]);
        s += fmaxf(v, 0.0f);
        s += __uint_as_float(gcolmin[i]);
    }

    #pragma unroll
    for (int off = 32; off > 0; off >>= 1)
        s += __shfl_down(s, off, 64);

    if ((threadIdx.x & 63) == 0) wsum[threadIdx.x >> 6] = s;
    __syncthreads();

    if (threadIdx.x == 0) {
        float acc = wsum[0] + wsum[1] + wsum[2] + wsum[3];
        atomicAdd(out, acc * (1.0f / ((float)BATCH * (float)NPTS)));
    }
}

extern "C" void kernel_launch(void* const* d_in, const int* in_sizes, int n_in,
                              void* d_out, int out_size, void* d_ws, size_t ws_size,
                              hipStream_t stream) {
    const float* pred   = (const float*)d_in[0];
    const float* target = (const float*)d_in[1];
    float* out = (float*)d_out;

    unsigned* gcolmin  = (unsigned*)d_ws;                          // 256 KB
    float* partial_row = (float*)((char*)d_ws + (256u << 10));     // 2 MB

    hipMemsetAsync(gcolmin, 0x7F, (size_t)BATCH * NPTS * 4, stream);  // sentinel
    hipMemsetAsync(out, 0, sizeof(float), stream);

    chamfer_mfma<<<dim3(CS * PANELS, BATCH), BLK, 0, stream>>>(
        pred, target, gcolmin, partial_row);
    chamfer_sum<<<dim3(32), 256, 0, stream>>>(gcolmin, partial_row, out);
}

// Round 11
// 97.290 us; speedup vs baseline: 1.2351x; 1.0069x over previous
//
#include <hip/hip_runtime.h>
#include <math.h>

#define NPTS   4096
#define BATCH  16
#define NT     128                        // 32-point tiles per cloud
#define CS     8                          // A-tile (sweep) splits
#define TPC    (NT / CS)                  // 16 A-tiles staged per block
#define BLK    256                        // 4 waves
#define BT_PER_BLK 8                      // 4 waves x 2 B-tiles
#define GRID_Y (NT / BT_PER_BLK)          // 16

typedef __attribute__((ext_vector_type(8)))  short bf16x8;
typedef __attribute__((ext_vector_type(16))) float f32x16;

static __device__ __forceinline__ unsigned short f2bf(float x) {
    unsigned u = __float_as_uint(x);
    unsigned r = 0x7FFFu + ((u >> 16) & 1u);     // RNE
    return (unsigned short)((u + r) >> 16);
}
static __device__ __forceinline__ float bf2f(unsigned short h) {
    return __uint_as_float(((unsigned)h) << 16);
}
static __device__ __forceinline__ float min3f(float a, float b, float c) {
    return fminf(fminf(a, b), c);                // fuses to v_min3_f32
}
// min of one acc's 16 elements (= 16 rows of this lane's column): 8 ops
static __device__ __forceinline__ float tree16(const f32x16& a) {
    float t0 = min3f(a[0],  a[1],  a[2]);
    float t1 = min3f(a[3],  a[4],  a[5]);
    float t2 = min3f(a[6],  a[7],  a[8]);
    float t3 = min3f(a[9],  a[10], a[11]);
    float t4 = min3f(a[12], a[13], a[14]);
    return fminf(min3f(t0, t1, t2), min3f(t3, t4, a[15]));
}

// ---------------------------------------------------------------------------
// K-slot bilinear form (validated rounds 4-9, absmax 0.0):
//   D = |q - r|^2 ~= qq + rr - 2(qh.rh + ql.rh + qh.rl)   (q=A-side, r=B-side)
// A-style frag of a point: k0-2 -2h, k3-5 -2l, k6-8 -2h(pairs B-lo), k9,10
// norms, k11,12 ones; B-style: k0-5 h, k6,7 l(xy), k8 l(z), k9,10 ones,
// k11,12 norms. Each direction is its OWN product with the min-axis on the
// A side (C/D layout: lane owns col=l&31, 16 rows), so the min is a pure
// in-register min3 tree + ONE shfl_xor(32) per wave — no shuffle storm,
// no atomics, no sentinels. Fragments precomputed once by prep_frags.
// ws: frags 4 x 2MB at 0; partial[dir][b][cs][4096] (4 MB) at 8MB.
// (Round 10 was an infra failure — identical resubmission of the round-9
// proposal so the prediction can be tested.)
// ---------------------------------------------------------------------------

__global__ __launch_bounds__(256) void prep_frags(
    const float* __restrict__ pred, const float* __restrict__ target,
    bf16x8* __restrict__ afp, bf16x8* __restrict__ bfp,
    bf16x8* __restrict__ aft, bf16x8* __restrict__ bft)
{
    const int id   = blockIdx.x * 256 + threadIdx.x;    // 0..131071
    const int l    = id & 63;
    const int tile = (id >> 6) & (NT - 1);
    const int b    = id >> 13;
    const int pt   = tile * 32 + (l & 31);
    const short one = (short)0x3F80;

    #pragma unroll
    for (int s = 0; s < 2; ++s) {
        const float* src = s ? target : pred;
        bf16x8* fa = s ? aft : afp;
        bf16x8* fb = s ? bft : bfp;

        const float* p = src + ((size_t)b * NPTS + pt) * 3;
        float x = p[0], y = p[1], z = p[2];
        unsigned short hx = f2bf(x), hy = f2bf(y), hz = f2bf(z);
        unsigned short lx = f2bf(x - bf2f(hx));
        unsigned short ly = f2bf(y - bf2f(hy));
        unsigned short lz = f2bf(z - bf2f(hz));
        unsigned short n2hx = f2bf(-2.0f * bf2f(hx));
        unsigned short n2hy = f2bf(-2.0f * bf2f(hy));
        unsigned short n2hz = f2bf(-2.0f * bf2f(hz));
        unsigned short n2lx = f2bf(-2.0f * bf2f(lx));
        unsigned short n2ly = f2bf(-2.0f * bf2f(ly));
        unsigned short n2lz = f2bf(-2.0f * bf2f(lz));
        float nn = fmaf(z, z, fmaf(y, y, x * x));
        unsigned short nh = f2bf(nn);
        unsigned short nl = f2bf(nn - bf2f(nh));

        bf16x8 va, vb;
        if (l < 32) {
            va = (bf16x8){(short)n2hx, (short)n2hy, (short)n2hz,
                          (short)n2lx, (short)n2ly, (short)n2lz,
                          (short)n2hx, (short)n2hy};
            vb = (bf16x8){(short)hx, (short)hy, (short)hz,
                          (short)hx, (short)hy, (short)hz,
                          (short)lx, (short)ly};
        } else {
            va = (bf16x8){(short)n2hz, (short)nh, (short)nl, one, one, 0, 0, 0};
            vb = (bf16x8){(short)lz, one, one, (short)nh, (short)nl, 0, 0, 0};
        }
        fa[id] = va;
        fb[id] = vb;
    }
}

// Block: (cs, B-tile group, b*2+dir). Stages TPC A-tiles in LDS; each wave
// owns 2 B-tiles and sweeps: 1 ds_read + 2 MFMA + 2 trees + 2 min per A-tile.
__global__ __launch_bounds__(BLK) void chamfer_mfma(
    const bf16x8* __restrict__ afp, const bf16x8* __restrict__ bfp,
    const bf16x8* __restrict__ aft, const bf16x8* __restrict__ bft,
    float* __restrict__ partial)
{
    __shared__ __align__(16) bf16x8 sA[TPC * 64];   // 16 KB

    const int cs  = blockIdx.x;
    const int yg  = blockIdx.y;
    const int dir = blockIdx.z & 1;     // 0: min over targets per pred point
    const int b   = blockIdx.z >> 1;
    const int t   = threadIdx.x;
    const int w   = t >> 6;
    const int l   = t & 63;

    const bf16x8* Asrc = dir ? afp : aft;   // swept side (rows = min axis)
    const bf16x8* Bsrc = dir ? bft : bfp;   // owned side (cols = output)

    // ---- stage A-frags for this cs range (pure copy, no conversion) ----
    const size_t abase = ((size_t)b * NT + cs * TPC) * 64;
    for (int e = t; e < TPC * 64; e += BLK) sA[e] = Asrc[abase + e];

    // ---- this wave's 2 B-tiles ----
    const int bt0 = (yg * 4 + w) * 2;
    bf16x8 bf0 = Bsrc[((size_t)b * NT + bt0)     * 64 + l];
    bf16x8 bf1 = Bsrc[((size_t)b * NT + bt0 + 1) * 64 + l];

    __syncthreads();

    f32x16 zacc;
    #pragma unroll
    for (int i = 0; i < 16; ++i) zacc[i] = 0.0f;

    float cm0 = INFINITY, cm1 = INFINITY;

    #pragma unroll 2
    for (int at = 0; at < TPC; ++at) {
        bf16x8 av = sA[at * 64 + l];
        f32x16 a0 = __builtin_amdgcn_mfma_f32_32x32x16_bf16(av, bf0, zacc, 0, 0, 0);
        f32x16 a1 = __builtin_amdgcn_mfma_f32_32x32x16_bf16(av, bf1, zacc, 0, 0, 0);
        cm0 = fminf(cm0, tree16(a0));
        cm1 = fminf(cm1, tree16(a1));
    }

    // combine the two lane-halves (rows split across l and l^32), store
    cm0 = fminf(cm0, __shfl_xor(cm0, 32, 64));
    cm1 = fminf(cm1, __shfl_xor(cm1, 32, 64));
    if (l < 32) {
        float* pb = partial + (((size_t)dir * BATCH + b) * CS + cs) * NPTS;
        pb[bt0 * 32 + l]        = cm0;
        pb[(bt0 + 1) * 32 + l]  = cm1;
    }
}

// Final: min over CS sweep-partials per point, clamp, sum, scale, atomicAdd.
__global__ __launch_bounds__(256) void chamfer_sum(
    const float* __restrict__ partial, float* __restrict__ out)
{
    __shared__ float wsum[4];
    const int gid = blockIdx.x * 256 + threadIdx.x;   // 32 blocks = 8192 threads

    float s = 0.0f;
    for (int i = gid; i < 2 * BATCH * NPTS; i += 8192) {
        const int db  = i >> 12;          // dir*BATCH + b
        const int row = i & (NPTS - 1);
        const float* p = partial + (size_t)db * CS * NPTS + row;
        float v = p[0];
        #pragma unroll
        for (int c = 1; c < CS; ++c) v = fminf(v, p[(size_t)c * NPTS]);
        s += fmaxf(v, 0.0f);
    }

    #pragma unroll
    for (int off = 32; off > 0; off >>= 1)
        s += __shfl_down(s, off, 64);

    if ((threadIdx.x & 63) == 0) wsum[threadIdx.x >> 6] = s;
    __syncthreads();

    if (threadIdx.x == 0) {
        float acc = wsum[0] + wsum[1] + wsum[2] + wsum[3];
        atomicAdd(out, acc * (1.0f / ((float)BATCH * (float)NPTS)));
    }
}

extern "C" void kernel_launch(void* const* d_in, const int* in_sizes, int n_in,
                              void* d_out, int out_size, void* d_ws, size_t ws_size,
                              hipStream_t stream) {
    const float* pred   = (const float*)d_in[0];
    const float* target = (const float*)d_in[1];
    float* out = (float*)d_out;

    char* ws = (char*)d_ws;
    bf16x8* afp = (bf16x8*)(ws + 0 * (2u << 20));   // A-style pred
    bf16x8* bfp = (bf16x8*)(ws + 1 * (2u << 20));   // B-style pred
    bf16x8* aft = (bf16x8*)(ws + 2 * (2u << 20));   // A-style target
    bf16x8* bft = (bf16x8*)(ws + 3 * (2u << 20));   // B-style target
    float* partial = (float*)(ws + 4 * (2u << 20)); // 4 MB, each slot written once

    hipMemsetAsync(out, 0, sizeof(float), stream);

    prep_frags<<<dim3(512), 256, 0, stream>>>(pred, target, afp, bfp, aft, bft);
    chamfer_mfma<<<dim3(CS, GRID_Y, BATCH * 2), BLK, 0, stream>>>(
        afp, bfp, aft, bft, partial);
    chamfer_sum<<<dim3(32), 256, 0, stream>>>(partial, out);
}